// Round 2
// baseline (300.483 us; speedup 1.0000x reference)
//
#include <hip/hip_runtime.h>
#include <stdint.h>

#define NW   2048
#define OBS  512
#define HS   512
#define HS2  512
#define HM   256
#define CTX  128
#define ACT  18
#define RPB  8      // rows per block
#define T    512    // threads per block

// ---------------- threefry2x32 (key = (0,42)), 20 rounds ----------------
#define TFR(x0, x1, R) { x0 += x1; x1 = (x1 << R) | (x1 >> (32 - R)); x1 ^= x0; }

__device__ __forceinline__ void threefry_0_42(uint32_t x0, uint32_t x1,
                                              uint32_t& o0, uint32_t& o1) {
    const uint32_t ks0 = 0u;
    const uint32_t ks1 = 42u;
    const uint32_t ks2 = 0x1BD11BDAu ^ ks0 ^ ks1;
    x0 += ks0; x1 += ks1;
    TFR(x0, x1, 13) TFR(x0, x1, 15) TFR(x0, x1, 26) TFR(x0, x1, 6)
    x0 += ks1; x1 += ks2 + 1u;
    TFR(x0, x1, 17) TFR(x0, x1, 29) TFR(x0, x1, 16) TFR(x0, x1, 24)
    x0 += ks2; x1 += ks0 + 2u;
    TFR(x0, x1, 13) TFR(x0, x1, 15) TFR(x0, x1, 26) TFR(x0, x1, 6)
    x0 += ks0; x1 += ks1 + 3u;
    TFR(x0, x1, 17) TFR(x0, x1, 29) TFR(x0, x1, 16) TFR(x0, x1, 24)
    x0 += ks1; x1 += ks2 + 4u;
    TFR(x0, x1, 13) TFR(x0, x1, 15) TFR(x0, x1, 26) TFR(x0, x1, 6)
    x0 += ks2; x1 += ks0 + 5u;
    o0 = x0; o1 = x1;
}

// Gumbel noise element (row, a) of shape (NW, ACT), matching
// jax.random.gumbel(key(42), (NW, ACT)) under jax_threefry_partitionable=True
// (default since jax 0.4.36): per-element 64-bit counter = linear index,
// block = (hi, lo) = (0, n), 32-bit output = out0 ^ out1 (xor-fold).
__device__ __forceinline__ float gumbel_ra(int row, int a) {
    uint32_t n = (uint32_t)(row * ACT + a);
    uint32_t o0, o1;
    threefry_0_42(0u, n, o0, o1);
    uint32_t bits = o0 ^ o1;
    uint32_t fb = (bits >> 9) | 0x3F800000u;
    float f = __uint_as_float(fb) - 1.0f;            // uniform [0,1)
    const float tiny = 1.17549435e-38f;
    float u = (f < tiny) ? tiny : f;                 // max(tiny, f*(1-tiny)+tiny) == max(tiny, f) in f32
    return -logf(-logf(u));
}

__global__ __launch_bounds__(T) void iamgru_policy_kernel(
    const float* __restrict__ obs,   const float* __restrict__ hmem,
    const float* __restrict__ W1,    const float* __restrict__ b1,
    const float* __restrict__ Wc,    const float* __restrict__ bc,
    const float* __restrict__ Wa,    const float* __restrict__ ba,
    const float* __restrict__ W_ih,  const float* __restrict__ b_ih,
    const float* __restrict__ W_hh,  const float* __restrict__ b_hh,
    const float* __restrict__ W2,    const float* __restrict__ b2,
    const float* __restrict__ Wact,  const float* __restrict__ bact,
    const float* __restrict__ Wcrit, const float* __restrict__ bcrit,
    float* __restrict__ out)
{
    __shared__ float s_obs[RPB][OBS];     // 16 KB
    __shared__ float s_h[RPB][HM];        //  8 KB  (hp, later overwritten by hnew)
    __shared__ float s_feat[RPB][HS];     // 16 KB
    __shared__ float s_hterm[RPB][CTX];   //  4 KB
    __shared__ float s_buf[RPB][HS];      // 16 KB  (alog, later out2)
    __shared__ float s_wc0[CTX];
    __shared__ float s_wa[CTX];
    __shared__ float s_x[RPB];

    const int tid  = threadIdx.x;
    const int row0 = blockIdx.x * RPB;

    // ---- stage 0: stage obs rows + h rows into LDS ----
    for (int i = tid; i < RPB * OBS; i += T) {
        int r = i >> 9, o = i & (OBS - 1);
        s_obs[r][o] = obs[(row0 + r) * OBS + o];
    }
    for (int i = tid; i < RPB * HM; i += T) {
        int r = i >> 8, m = i & (HM - 1);
        s_h[r][m] = hmem[(row0 + r) * HM + m];
    }
    if (tid < CTX) { s_wc0[tid] = Wc[tid * (HM + 1)]; s_wa[tid] = Wa[tid]; }
    __syncthreads();

    // ---- stage 1: feat = relu(obs @ W1^T + b1)  (thread = output col) ----
    {
        const int c = tid;
        float acc[RPB];
        float bias = b1[c];
        #pragma unroll
        for (int r = 0; r < RPB; ++r) acc[r] = bias;
        const float* w = &W1[c * OBS];
        for (int k = 0; k < OBS; ++k) {
            float wv = w[k];
            #pragma unroll
            for (int r = 0; r < RPB; ++r) acc[r] += s_obs[r][k] * wv;
        }
        #pragma unroll
        for (int r = 0; r < RPB; ++r) s_feat[r][c] = fmaxf(acc[r], 0.0f);
    }

    // ---- stage 2: h_term = h @ Wc[:,1:]^T + bc  (threads 0..127) ----
    if (tid < CTX) {
        const int c = tid;
        const float* w = &Wc[c * (HM + 1) + 1];
        float acc[RPB];
        float bias = bc[c];
        #pragma unroll
        for (int r = 0; r < RPB; ++r) acc[r] = bias;
        for (int m = 0; m < HM; ++m) {
            float wv = w[m];
            #pragma unroll
            for (int r = 0; r < RPB; ++r) acc[r] += s_h[r][m] * wv;
        }
        #pragma unroll
        for (int r = 0; r < RPB; ++r) s_hterm[r][c] = acc[r];
    }
    __syncthreads();

    // ---- stage 3: alog[r][o] = ba + sum_c Wa[c]*tanh(obs[r][o]*Wc0[c] + hterm[r][c]) ----
    {
        const float ba0 = ba[0];
        const int o = tid;
        #pragma unroll
        for (int r = 0; r < RPB; ++r) {
            float ob = s_obs[r][o];
            float s = 0.0f;
            for (int c = 0; c < CTX; ++c)
                s += s_wa[c] * tanhf(ob * s_wc0[c] + s_hterm[r][c]);
            s_buf[r][o] = s + ba0;
        }
    }
    __syncthreads();

    // ---- stage 4: softmax over o + dset -> x[r]  (wave per row) ----
    {
        const int w = tid >> 6, lane = tid & 63;
        const int r = w;
        float m = -1e30f;
        for (int o = lane; o < OBS; o += 64) m = fmaxf(m, s_buf[r][o]);
        #pragma unroll
        for (int d = 32; d >= 1; d >>= 1) m = fmaxf(m, __shfl_xor(m, d));
        float se = 0.0f, sw = 0.0f;
        for (int o = lane; o < OBS; o += 64) {
            float e = expf(s_buf[r][o] - m);
            se += e; sw += e * s_obs[r][o];
        }
        #pragma unroll
        for (int d = 32; d >= 1; d >>= 1) { se += __shfl_xor(se, d); sw += __shfl_xor(sw, d); }
        if (lane == 0) s_x[r] = sw / se;
    }
    __syncthreads();

    // ---- stage 5: GRU cell. thread -> gate column j (=tid&255), rows half (tid>>8) ----
    {
        const int j = tid & (HM - 1);
        const int half = tid >> 8;           // 0 or 1
        const int rbase = half * (RPB / 2);  // rows rbase..rbase+3
        float accr[4], accz[4], accn[4];
        float bhr = b_hh[j], bhz = b_hh[HM + j], bhn = b_hh[2 * HM + j];
        #pragma unroll
        for (int q = 0; q < 4; ++q) { accr[q] = bhr; accz[q] = bhz; accn[q] = bhn; }
        const float* wr = &W_hh[j * HM];
        const float* wz = &W_hh[(HM + j) * HM];
        const float* wn = &W_hh[(2 * HM + j) * HM];
        for (int m = 0; m < HM; ++m) {
            float wvr = wr[m], wvz = wz[m], wvn = wn[m];
            #pragma unroll
            for (int q = 0; q < 4; ++q) {
                float hv = s_h[rbase + q][m];
                accr[q] += hv * wvr; accz[q] += hv * wvz; accn[q] += hv * wvn;
            }
        }
        float wih_r = W_ih[j], wih_z = W_ih[HM + j], wih_n = W_ih[2 * HM + j];
        float bih_r = b_ih[j], bih_z = b_ih[HM + j], bih_n = b_ih[2 * HM + j];
        float hnew[4];
        #pragma unroll
        for (int q = 0; q < 4; ++q) {
            const int r = rbase + q;
            float x  = s_x[r];
            float hp = s_h[r][j];
            float gir = x * wih_r + bih_r;
            float giz = x * wih_z + bih_z;
            float gin = x * wih_n + bih_n;
            float rg = 1.0f / (1.0f + expf(-(gir + accr[q])));
            float zg = 1.0f / (1.0f + expf(-(giz + accz[q])));
            float ng = tanhf(gin + rg * accn[q]);
            hnew[q] = (1.0f - zg) * ng + zg * hp;
        }
        __syncthreads();                       // all hp reads done
        #pragma unroll
        for (int q = 0; q < 4; ++q) s_h[rbase + q][j] = hnew[q];
    }
    __syncthreads();

    // ---- stage 6: out2 = relu([feat, hnew] @ W2^T + b2)  (thread = col) ----
    {
        const int c = tid;
        float acc[RPB];
        float bias = b2[c];
        #pragma unroll
        for (int r = 0; r < RPB; ++r) acc[r] = bias;
        const float* w = &W2[c * (HS + HM)];
        for (int k = 0; k < HS; ++k) {
            float wv = w[k];
            #pragma unroll
            for (int r = 0; r < RPB; ++r) acc[r] += s_feat[r][k] * wv;
        }
        for (int k = 0; k < HM; ++k) {
            float wv = w[HS + k];
            #pragma unroll
            for (int r = 0; r < RPB; ++r) acc[r] += s_h[r][k] * wv;
        }
        #pragma unroll
        for (int r = 0; r < RPB; ++r) s_buf[r][c] = fmaxf(acc[r], 0.0f);
    }
    __syncthreads();

    // ---- stage 7/8: heads + categorical sampling (wave per row) ----
    {
        const int w = tid >> 6, lane = tid & 63;
        const int r = w;
        const int grow = row0 + r;

        float lg = 0.0f;
        if (lane < ACT) {
            const float* wa = &Wact[lane * HS2];
            float a = bact[lane];
            for (int k = 0; k < HS2; ++k) a += wa[k] * s_buf[r][k];
            lg = a;
        }
        float v = 0.0f;
        if (lane == 63) {
            float a = bcrit[0];
            for (int k = 0; k < HS2; ++k) a += Wcrit[k] * s_buf[r][k];
            v = a;
        }
        float g = (lane < ACT) ? gumbel_ra(grow, lane) : 0.0f;

        // gather logits + gumbel across lanes (all lanes execute shfl)
        float la[ACT];
        float best = -1e30f; int amax = 0;
        float mx = -1e30f;
        #pragma unroll
        for (int a = 0; a < ACT; ++a) {
            float l_ = __shfl(lg, a);
            float g_ = __shfl(g, a);
            la[a] = l_;
            float y = l_ + g_;
            if (y > best) { best = y; amax = a; }   // first-max tie-break
            mx = fmaxf(mx, l_);
        }
        float se = 0.0f;
        #pragma unroll
        for (int a = 0; a < ACT; ++a) se += expf(la[a] - mx);
        float lse = mx + logf(se);
        float lp = la[amax] - lse;
        float vv = __shfl(v, 63);

        if (lane == 0) {
            out[grow]           = (float)amax;  // action
            out[NW + grow]      = vv;           // value
            out[2 * NW + grow]  = lp;           // log_prob
        }
    }
}

extern "C" void kernel_launch(void* const* d_in, const int* in_sizes, int n_in,
                              void* d_out, int out_size, void* d_ws, size_t ws_size,
                              hipStream_t stream) {
    const float* obs   = (const float*)d_in[0];
    const float* hmem  = (const float*)d_in[1];
    const float* W1    = (const float*)d_in[2];
    const float* b1    = (const float*)d_in[3];
    const float* Wc    = (const float*)d_in[4];
    const float* bc    = (const float*)d_in[5];
    const float* Wa    = (const float*)d_in[6];
    const float* ba    = (const float*)d_in[7];
    const float* W_ih  = (const float*)d_in[8];
    const float* b_ih  = (const float*)d_in[9];
    const float* W_hh  = (const float*)d_in[10];
    const float* b_hh  = (const float*)d_in[11];
    const float* W2    = (const float*)d_in[12];
    const float* b2    = (const float*)d_in[13];
    const float* Wact  = (const float*)d_in[14];
    const float* bact  = (const float*)d_in[15];
    const float* Wcrit = (const float*)d_in[16];
    const float* bcrit = (const float*)d_in[17];

    iamgru_policy_kernel<<<NW / RPB, T, 0, stream>>>(
        obs, hmem, W1, b1, Wc, bc, Wa, ba, W_ih, b_ih, W_hh, b_hh,
        W2, b2, Wact, bact, Wcrit, bcrit, (float*)d_out);
}